// Round 4
// baseline (455.668 us; speedup 1.0000x reference)
//
#include <hip/hip_runtime.h>

// SimpleGNN 2-layer GCN, linear collapse + 2-level bucketed aggregation.
//
//   out = N^2 x W12 + (N 1) c1^T + 1 b2^T,   N = D^-1/2 (A+I) D^-1/2
//   W12 = W1@W2 (64x10), c1 = b1@W2.
//
// Pipeline:
//   1. bucket edges by dst>>7 (782 buckets x 128 nodes): count -> scan ->
//      scatter (src:u32, dst&127:u8), per-block LDS histograms so global
//      writes are contiguous runs (no 4B-random-store write amplification).
//   2. deg/dis per bucket from the u8 dst stream (LDS histogram).
//   3. yd[n] = [dis*x@W12 (10ch), dis, 0,0,0,0,0]  (16-float row = 1 line)
//   4. agg pass 1 (bucket-local LDS acc, ds_add_f32): zd = dis (x) N yd-ish:
//        zd[n][c<10] = dis^2 * (yd[n][c] + sum_src yd[s][c])
//        zd[n][10]   = dis   * (yd[n][10] + sum_src yd[s][10])   (= (N 1)[n])
//   5. agg pass 2: out[n][c] = dis*(zd[n][c]+sum zd[s][c]) + zd[n][10]*c1[c] + b2[c]

#define NN 100000
#define NE 1600000
#define NPB 128            // nodes per bucket
#define NB 782             // ceil(NN/NPB); NB*NPB = 100096
#define CHUNK 16384        // edges per bucketing block
#define NCB 98             // ceil(NE/CHUNK)

__global__ void k_bzero(int* __restrict__ bcnt) {
    int t = threadIdx.x;
    if (t < NB) bcnt[t] = 0;
}

__global__ __launch_bounds__(256) void k_b_count(const int* __restrict__ dst,
                                                 int* __restrict__ bcnt) {
    __shared__ int h[NB];
    for (int i = threadIdx.x; i < NB; i += 256) h[i] = 0;
    __syncthreads();
    int e0 = blockIdx.x * CHUNK, e1 = min(e0 + CHUNK, NE);
    for (int e = e0 + threadIdx.x; e < e1; e += 256)
        atomicAdd(&h[dst[e] >> 7], 1);
    __syncthreads();
    for (int i = threadIdx.x; i < NB; i += 256)
        if (h[i]) atomicAdd(&bcnt[i], h[i]);
}

__global__ __launch_bounds__(1024) void k_b_scan(const int* __restrict__ bcnt,
                                                 int* __restrict__ bptr,
                                                 int* __restrict__ bcur) {
    __shared__ int sc[1024];
    int t = threadIdx.x;
    int v = (t < NB) ? bcnt[t] : 0;
    sc[t] = v; __syncthreads();
    for (int off = 1; off < 1024; off <<= 1) {
        int a = (t >= off) ? sc[t - off] : 0;
        __syncthreads();
        sc[t] += a;
        __syncthreads();
    }
    if (t < NB) { int e = sc[t] - v; bptr[t] = e; bcur[t] = e; }
    if (t == 0) bptr[NB] = NE;
}

__global__ __launch_bounds__(256) void k_b_scatter(const int* __restrict__ src,
                                                   const int* __restrict__ dst,
                                                   int* __restrict__ bcur,
                                                   int* __restrict__ bsrc,
                                                   unsigned char* __restrict__ bdst8) {
    __shared__ int h[NB];
    __shared__ int cur[NB];
    for (int i = threadIdx.x; i < NB; i += 256) h[i] = 0;
    __syncthreads();
    int e0 = blockIdx.x * CHUNK, e1 = min(e0 + CHUNK, NE);
    for (int e = e0 + threadIdx.x; e < e1; e += 256)
        atomicAdd(&h[dst[e] >> 7], 1);
    __syncthreads();
    for (int i = threadIdx.x; i < NB; i += 256)
        if (h[i]) cur[i] = atomicAdd(&bcur[i], h[i]);
    __syncthreads();
    for (int e = e0 + threadIdx.x; e < e1; e += 256) {
        int d = dst[e];
        int b = d >> 7;
        int p = atomicAdd(&cur[b], 1);
        bsrc[p] = src[e];
        bdst8[p] = (unsigned char)(d & 127);
    }
}

// Per-bucket in-degree -> dis = rsqrt(deg+1).
__global__ __launch_bounds__(256) void k_deg(const unsigned char* __restrict__ bdst8,
                                             const int* __restrict__ bptr,
                                             float* __restrict__ dis) {
    __shared__ int cnt[NPB];
    int b = blockIdx.x;
    if (threadIdx.x < NPB) cnt[threadIdx.x] = 0;
    __syncthreads();
    int p0 = bptr[b], p1 = bptr[b + 1];
    for (int j = p0 + threadIdx.x; j < p1; j += 256)
        atomicAdd(&cnt[bdst8[j]], 1);
    __syncthreads();
    if (threadIdx.x < NPB) {
        int n = b * NPB + threadIdx.x;
        if (n < NN) dis[n] = rsqrtf((float)cnt[threadIdx.x] + 1.0f);
    }
}

// W12 = W1 @ W2 ; c1 = b1 @ W2. One block.
__global__ __launch_bounds__(256) void k_small(const float* __restrict__ W1,
                                               const float* __restrict__ W2,
                                               const float* __restrict__ b1,
                                               float* __restrict__ W12,
                                               float* __restrict__ c1) {
    int t = threadIdx.x;
    for (int o = t; o < 640; o += 256) {
        int k = o / 10, c = o - k * 10;
        float acc = 0.f;
        #pragma unroll
        for (int m = 0; m < 64; ++m) acc = fmaf(W1[k * 64 + m], W2[m * 10 + c], acc);
        W12[o] = acc;
    }
    if (t < 10) {
        float acc = 0.f;
        #pragma unroll
        for (int m = 0; m < 64; ++m) acc = fmaf(b1[m], W2[m * 10 + t], acc);
        c1[t] = acc;
    }
}

// yd[r] = [dis[r]*(x[r]@W12) (c<10), dis[r], zeros]; row stride 16 floats.
__global__ __launch_bounds__(256) void k_proj(const float* __restrict__ x,
                                              const float* __restrict__ W12,
                                              const float* __restrict__ dis,
                                              float* __restrict__ yd) {
    __shared__ float Wl[640];
    __shared__ float tile[64][65];
    __shared__ float ot[64][16];
    for (int i = threadIdx.x; i < 640; i += 256) Wl[i] = W12[i];
    int base = blockIdx.x * 64;
    int nrows = min(64, NN - base);
    for (int i = threadIdx.x; i < nrows * 64; i += 256) {
        int r = i >> 6, k = i & 63;
        tile[r][k] = x[(base + r) * 64 + k];
    }
    for (int i = threadIdx.x; i < 64 * 16; i += 256) ((float*)ot)[i] = 0.f;
    __syncthreads();
    for (int o = threadIdx.x; o < nrows * 10; o += 256) {
        int r = o / 10, c = o - r * 10;
        float acc = 0.f;
        #pragma unroll
        for (int k = 0; k < 64; ++k) acc = fmaf(tile[r][k], Wl[k * 10 + c], acc);
        ot[r][c] = dis[base + r] * acc;
    }
    if (threadIdx.x < nrows) ot[threadIdx.x][10] = dis[base + threadIdx.x];
    __syncthreads();
    for (int i = threadIdx.x; i < nrows * 16; i += 256)
        yd[base * 16 + i] = ((const float*)ot)[i];
}

// Bucket-local aggregation pass 1: acc seeded with self term, edges add
// yd[src] lines via LDS float atomics; writeout scales by dis^2 (dis for ch10).
__global__ __launch_bounds__(512) void k_agg1(const float* __restrict__ yd,
                                              const float* __restrict__ dis,
                                              const int* __restrict__ bptr,
                                              const int* __restrict__ bsrc,
                                              const unsigned char* __restrict__ bdst8,
                                              float* __restrict__ zd) {
    __shared__ float acc[NPB][16];
    int b = blockIdx.x, base = b * NPB;
    for (int i = threadIdx.x; i < NPB * 16; i += 512)
        ((float*)acc)[i] = yd[base * 16 + i];   // self terms (tail rows unused)
    __syncthreads();
    int p0 = bptr[b], p1 = bptr[b + 1];
    int g = threadIdx.x >> 4, lane = threadIdx.x & 15;   // 32 groups of 16
    int j = p0 + g;
    for (; j + 32 < p1; j += 64) {
        int s0 = bsrc[j], s1 = bsrc[j + 32];
        int d0 = bdst8[j], d1 = bdst8[j + 32];
        float v0 = yd[s0 * 16 + lane];
        float v1 = yd[s1 * 16 + lane];
        atomicAdd(&acc[d0][lane], v0);
        atomicAdd(&acc[d1][lane], v1);
    }
    if (j < p1) {
        int s0 = bsrc[j], d0 = bdst8[j];
        atomicAdd(&acc[d0][lane], yd[s0 * 16 + lane]);
    }
    __syncthreads();
    for (int i = threadIdx.x; i < NPB * 16; i += 512) {
        int r = i >> 4, c = i & 15;
        int n = base + r;
        if (n < NN) {
            float d = dis[n];
            float scale = (c == 10) ? d : d * d;
            zd[n * 16 + c] = scale * ((const float*)acc)[i];
        }
    }
}

// Pass 2: same structure over zd; out = dis*acc + n1*c1 + b2.
__global__ __launch_bounds__(512) void k_agg2(const float* __restrict__ zd,
                                              const float* __restrict__ dis,
                                              const int* __restrict__ bptr,
                                              const int* __restrict__ bsrc,
                                              const unsigned char* __restrict__ bdst8,
                                              const float* __restrict__ c1,
                                              const float* __restrict__ b2,
                                              float* __restrict__ out) {
    __shared__ float acc[NPB][16];
    int b = blockIdx.x, base = b * NPB;
    for (int i = threadIdx.x; i < NPB * 16; i += 512)
        ((float*)acc)[i] = zd[base * 16 + i];
    __syncthreads();
    int p0 = bptr[b], p1 = bptr[b + 1];
    int g = threadIdx.x >> 4, lane = threadIdx.x & 15;
    int j = p0 + g;
    for (; j + 32 < p1; j += 64) {
        int s0 = bsrc[j], s1 = bsrc[j + 32];
        int d0 = bdst8[j], d1 = bdst8[j + 32];
        float v0 = zd[s0 * 16 + lane];
        float v1 = zd[s1 * 16 + lane];
        atomicAdd(&acc[d0][lane], v0);
        atomicAdd(&acc[d1][lane], v1);
    }
    if (j < p1) {
        int s0 = bsrc[j], d0 = bdst8[j];
        atomicAdd(&acc[d0][lane], zd[s0 * 16 + lane]);
    }
    __syncthreads();
    for (int o = threadIdx.x; o < NPB * 10; o += 512) {
        int r = o / 10, c = o - r * 10;
        int n = base + r;
        if (n < NN) {
            float n1 = zd[n * 16 + 10];
            out[n * 10 + c] = fmaf(dis[n], acc[r][c], fmaf(n1, c1[c], b2[c]));
        }
    }
}

extern "C" void kernel_launch(void* const* d_in, const int* in_sizes, int n_in,
                              void* d_out, int out_size, void* d_ws, size_t ws_size,
                              hipStream_t stream) {
    const float* x  = (const float*)d_in[0];
    const float* W1 = (const float*)d_in[1];
    const float* b1 = (const float*)d_in[2];
    const float* W2 = (const float*)d_in[3];
    const float* b2 = (const float*)d_in[4];
    const int* edge = (const int*)d_in[5];   // [2, NE]: src row then dst row
    const int* src = edge;
    const int* dst = edge + NE;
    float* out = (float*)d_out;

    // Workspace layout (64B-aligned), total ~21.2 MB:
    char* W = (char*)d_ws;
    float* yd    = (float*)(W);                      // NN*16 f = 6,400,000 B
    float* zd    = (float*)(W + 6400000);            // NN*16 f = 6,400,000 B
    float* dis   = (float*)(W + 12800000);           // NN f
    int*   bsrc  = (int*)  (W + 13200000);           // NE i   = 6,400,000 B
    unsigned char* bdst8 = (unsigned char*)(W + 19600000);  // NE u8 = 1,600,000 B
    int*   bcnt  = (int*)  (W + 21200064);           // NB
    int*   bptr  = (int*)  (W + 21203264);           // NB+1
    int*   bcur  = (int*)  (W + 21206464);           // NB
    float* W12   = (float*)(W + 21209664);           // 640 f
    float* c1    = (float*)(W + 21212288);           // 10 f

    k_small    <<<1, 256, 0, stream>>>(W1, W2, b1, W12, c1);
    k_bzero    <<<1, 1024, 0, stream>>>(bcnt);
    k_b_count  <<<NCB, 256, 0, stream>>>(dst, bcnt);
    k_b_scan   <<<1, 1024, 0, stream>>>(bcnt, bptr, bcur);
    k_b_scatter<<<NCB, 256, 0, stream>>>(src, dst, bcur, bsrc, bdst8);
    k_deg      <<<NB, 256, 0, stream>>>(bdst8, bptr, dis);
    k_proj     <<<(NN + 63) / 64, 256, 0, stream>>>(x, W12, dis, yd);
    k_agg1     <<<NB, 512, 0, stream>>>(yd, dis, bptr, bsrc, bdst8, zd);
    k_agg2     <<<NB, 512, 0, stream>>>(zd, dis, bptr, bsrc, bdst8, c1, b2, out);
}

// Round 5
// 451.841 us; speedup vs baseline: 1.0085x; 1.0085x over previous
//
#include <hip/hip_runtime.h>

// SimpleGNN 2-layer GCN, linear collapse + 2-level bucketed aggregation.
//
//   out = N^2 x W12 + (N 1) c1^T + 1 b2^T,   N = D^-1/2 (A+I) D^-1/2
//   W12 = W1@W2 (64x10), c1 = b1@W2.
//
// Pipeline:
//   1. bucket edges by dst>>7 (782 buckets x 128 nodes): count -> scan ->
//      scatter (src:u32, dst&127:u8), per-block LDS histograms so global
//      writes are contiguous runs (no 4B-random-store write amplification).
//   2. deg/dis per bucket from the u8 dst stream (LDS histogram).
//   3. yd[n] = [dis*x@W12 (10ch), dis, 0...]  (16-float row = 1 cache line)
//   4. agg pass 1: bucket-local LDS acc (ds_add_f32), 1024-thr blocks,
//      4-deep unrolled gathers for latency hiding:
//        zd[n][c<10] = dis^2 * (yd[n][c] + sum_src yd[s][c])
//        zd[n][10]   = dis   * (yd[n][10] + sum_src yd[s][10])   (= (N 1)[n])
//   5. agg pass 2: out[n][c] = dis*(zd[n][c]+sum zd[s][c]) + zd[n][10]*c1[c] + b2[c]

#define NN 100000
#define NE 1600000
#define NPB 128            // nodes per bucket
#define NB 782             // ceil(NN/NPB); NB*NPB = 100096
#define CHUNK 16384        // edges per bucketing block
#define NCB 98             // ceil(NE/CHUNK)
#define AGG_THREADS 1024
#define AGG_G 64           // 16-lane groups per agg block

__global__ void k_bzero(int* __restrict__ bcnt) {
    int t = threadIdx.x;
    if (t < NB) bcnt[t] = 0;
}

__global__ __launch_bounds__(256) void k_b_count(const int* __restrict__ dst,
                                                 int* __restrict__ bcnt) {
    __shared__ int h[NB];
    for (int i = threadIdx.x; i < NB; i += 256) h[i] = 0;
    __syncthreads();
    int e0 = blockIdx.x * CHUNK, e1 = min(e0 + CHUNK, NE);
    for (int e = e0 + threadIdx.x; e < e1; e += 256)
        atomicAdd(&h[dst[e] >> 7], 1);
    __syncthreads();
    for (int i = threadIdx.x; i < NB; i += 256)
        if (h[i]) atomicAdd(&bcnt[i], h[i]);
}

__global__ __launch_bounds__(1024) void k_b_scan(const int* __restrict__ bcnt,
                                                 int* __restrict__ bptr,
                                                 int* __restrict__ bcur) {
    __shared__ int sc[1024];
    int t = threadIdx.x;
    int v = (t < NB) ? bcnt[t] : 0;
    sc[t] = v; __syncthreads();
    for (int off = 1; off < 1024; off <<= 1) {
        int a = (t >= off) ? sc[t - off] : 0;
        __syncthreads();
        sc[t] += a;
        __syncthreads();
    }
    if (t < NB) { int e = sc[t] - v; bptr[t] = e; bcur[t] = e; }
    if (t == 0) bptr[NB] = NE;
}

__global__ __launch_bounds__(256) void k_b_scatter(const int* __restrict__ src,
                                                   const int* __restrict__ dst,
                                                   int* __restrict__ bcur,
                                                   int* __restrict__ bsrc,
                                                   unsigned char* __restrict__ bdst8) {
    __shared__ int h[NB];
    __shared__ int cur[NB];
    for (int i = threadIdx.x; i < NB; i += 256) h[i] = 0;
    __syncthreads();
    int e0 = blockIdx.x * CHUNK, e1 = min(e0 + CHUNK, NE);
    for (int e = e0 + threadIdx.x; e < e1; e += 256)
        atomicAdd(&h[dst[e] >> 7], 1);
    __syncthreads();
    for (int i = threadIdx.x; i < NB; i += 256)
        if (h[i]) cur[i] = atomicAdd(&bcur[i], h[i]);
    __syncthreads();
    for (int e = e0 + threadIdx.x; e < e1; e += 256) {
        int d = dst[e];
        int b = d >> 7;
        int p = atomicAdd(&cur[b], 1);
        bsrc[p] = src[e];
        bdst8[p] = (unsigned char)(d & 127);
    }
}

// Per-bucket in-degree -> dis = rsqrt(deg+1).
__global__ __launch_bounds__(256) void k_deg(const unsigned char* __restrict__ bdst8,
                                             const int* __restrict__ bptr,
                                             float* __restrict__ dis) {
    __shared__ int cnt[NPB];
    int b = blockIdx.x;
    if (threadIdx.x < NPB) cnt[threadIdx.x] = 0;
    __syncthreads();
    int p0 = bptr[b], p1 = bptr[b + 1];
    for (int j = p0 + threadIdx.x; j < p1; j += 256)
        atomicAdd(&cnt[bdst8[j]], 1);
    __syncthreads();
    if (threadIdx.x < NPB) {
        int n = b * NPB + threadIdx.x;
        if (n < NN) dis[n] = rsqrtf((float)cnt[threadIdx.x] + 1.0f);
    }
}

// W12 = W1 @ W2 ; c1 = b1 @ W2. One block.
__global__ __launch_bounds__(256) void k_small(const float* __restrict__ W1,
                                               const float* __restrict__ W2,
                                               const float* __restrict__ b1,
                                               float* __restrict__ W12,
                                               float* __restrict__ c1) {
    int t = threadIdx.x;
    for (int o = t; o < 640; o += 256) {
        int k = o / 10, c = o - k * 10;
        float acc = 0.f;
        #pragma unroll
        for (int m = 0; m < 64; ++m) acc = fmaf(W1[k * 64 + m], W2[m * 10 + c], acc);
        W12[o] = acc;
    }
    if (t < 10) {
        float acc = 0.f;
        #pragma unroll
        for (int m = 0; m < 64; ++m) acc = fmaf(b1[m], W2[m * 10 + t], acc);
        c1[t] = acc;
    }
}

// yd[r] = [dis[r]*(x[r]@W12) (c<10), dis[r], zeros]; row stride 16 floats.
__global__ __launch_bounds__(256) void k_proj(const float* __restrict__ x,
                                              const float* __restrict__ W12,
                                              const float* __restrict__ dis,
                                              float* __restrict__ yd) {
    __shared__ float Wl[640];
    __shared__ float tile[64][65];
    __shared__ float ot[64][16];
    for (int i = threadIdx.x; i < 640; i += 256) Wl[i] = W12[i];
    int base = blockIdx.x * 64;
    int nrows = min(64, NN - base);
    for (int i = threadIdx.x; i < nrows * 64; i += 256) {
        int r = i >> 6, k = i & 63;
        tile[r][k] = x[(base + r) * 64 + k];
    }
    for (int i = threadIdx.x; i < 64 * 16; i += 256) ((float*)ot)[i] = 0.f;
    __syncthreads();
    for (int o = threadIdx.x; o < nrows * 10; o += 256) {
        int r = o / 10, c = o - r * 10;
        float acc = 0.f;
        #pragma unroll
        for (int k = 0; k < 64; ++k) acc = fmaf(tile[r][k], Wl[k * 10 + c], acc);
        ot[r][c] = dis[base + r] * acc;
    }
    if (threadIdx.x < nrows) ot[threadIdx.x][10] = dis[base + threadIdx.x];
    __syncthreads();
    for (int i = threadIdx.x; i < nrows * 16; i += 256)
        yd[base * 16 + i] = ((const float*)ot)[i];
}

// Agg pass 1: 1024 threads = 64 groups of 16 lanes; 4-deep unrolled gathers.
__global__ __launch_bounds__(1024) void k_agg1(const float* __restrict__ yd,
                                               const float* __restrict__ dis,
                                               const int* __restrict__ bptr,
                                               const int* __restrict__ bsrc,
                                               const unsigned char* __restrict__ bdst8,
                                               float* __restrict__ zd) {
    __shared__ float acc[NPB][16];
    int b = blockIdx.x, base = b * NPB;
    for (int i = threadIdx.x; i < NPB * 16; i += AGG_THREADS)
        ((float*)acc)[i] = (base * 16 + i < NN * 16) ? yd[base * 16 + i] : 0.f;
    __syncthreads();
    int p0 = bptr[b], p1 = bptr[b + 1];
    int g = threadIdx.x >> 4, lane = threadIdx.x & 15;
    int j = p0 + g;
    for (; j + 3 * AGG_G < p1; j += 4 * AGG_G) {
        int s0 = bsrc[j],             s1 = bsrc[j + AGG_G];
        int s2 = bsrc[j + 2 * AGG_G], s3 = bsrc[j + 3 * AGG_G];
        int d0 = bdst8[j],             d1 = bdst8[j + AGG_G];
        int d2 = bdst8[j + 2 * AGG_G], d3 = bdst8[j + 3 * AGG_G];
        float v0 = yd[s0 * 16 + lane];
        float v1 = yd[s1 * 16 + lane];
        float v2 = yd[s2 * 16 + lane];
        float v3 = yd[s3 * 16 + lane];
        atomicAdd(&acc[d0][lane], v0);
        atomicAdd(&acc[d1][lane], v1);
        atomicAdd(&acc[d2][lane], v2);
        atomicAdd(&acc[d3][lane], v3);
    }
    for (; j < p1; j += AGG_G) {
        int s = bsrc[j], d = bdst8[j];
        atomicAdd(&acc[d][lane], yd[s * 16 + lane]);
    }
    __syncthreads();
    for (int i = threadIdx.x; i < NPB * 16; i += AGG_THREADS) {
        int r = i >> 4, c = i & 15;
        int n = base + r;
        if (n < NN) {
            float d = dis[n];
            float scale = (c == 10) ? d : d * d;
            zd[n * 16 + c] = scale * ((const float*)acc)[i];
        }
    }
}

// Agg pass 2: same structure over zd; out = dis*acc + n1*c1 + b2.
__global__ __launch_bounds__(1024) void k_agg2(const float* __restrict__ zd,
                                               const float* __restrict__ dis,
                                               const int* __restrict__ bptr,
                                               const int* __restrict__ bsrc,
                                               const unsigned char* __restrict__ bdst8,
                                               const float* __restrict__ c1,
                                               const float* __restrict__ b2,
                                               float* __restrict__ out) {
    __shared__ float acc[NPB][16];
    int b = blockIdx.x, base = b * NPB;
    for (int i = threadIdx.x; i < NPB * 16; i += AGG_THREADS)
        ((float*)acc)[i] = (base * 16 + i < NN * 16) ? zd[base * 16 + i] : 0.f;
    __syncthreads();
    int p0 = bptr[b], p1 = bptr[b + 1];
    int g = threadIdx.x >> 4, lane = threadIdx.x & 15;
    int j = p0 + g;
    for (; j + 3 * AGG_G < p1; j += 4 * AGG_G) {
        int s0 = bsrc[j],             s1 = bsrc[j + AGG_G];
        int s2 = bsrc[j + 2 * AGG_G], s3 = bsrc[j + 3 * AGG_G];
        int d0 = bdst8[j],             d1 = bdst8[j + AGG_G];
        int d2 = bdst8[j + 2 * AGG_G], d3 = bdst8[j + 3 * AGG_G];
        float v0 = zd[s0 * 16 + lane];
        float v1 = zd[s1 * 16 + lane];
        float v2 = zd[s2 * 16 + lane];
        float v3 = zd[s3 * 16 + lane];
        atomicAdd(&acc[d0][lane], v0);
        atomicAdd(&acc[d1][lane], v1);
        atomicAdd(&acc[d2][lane], v2);
        atomicAdd(&acc[d3][lane], v3);
    }
    for (; j < p1; j += AGG_G) {
        int s = bsrc[j], d = bdst8[j];
        atomicAdd(&acc[d][lane], zd[s * 16 + lane]);
    }
    __syncthreads();
    for (int o = threadIdx.x; o < NPB * 10; o += AGG_THREADS) {
        int r = o / 10, c = o - r * 10;
        int n = base + r;
        if (n < NN) {
            float n1 = zd[n * 16 + 10];
            out[n * 10 + c] = fmaf(dis[n], acc[r][c], fmaf(n1, c1[c], b2[c]));
        }
    }
}

extern "C" void kernel_launch(void* const* d_in, const int* in_sizes, int n_in,
                              void* d_out, int out_size, void* d_ws, size_t ws_size,
                              hipStream_t stream) {
    const float* x  = (const float*)d_in[0];
    const float* W1 = (const float*)d_in[1];
    const float* b1 = (const float*)d_in[2];
    const float* W2 = (const float*)d_in[3];
    const float* b2 = (const float*)d_in[4];
    const int* edge = (const int*)d_in[5];   // [2, NE]: src row then dst row
    const int* src = edge;
    const int* dst = edge + NE;
    float* out = (float*)d_out;

    // Workspace layout (64B-aligned), total ~21.2 MB:
    char* W = (char*)d_ws;
    float* yd    = (float*)(W);                      // NN*16 f = 6,400,000 B
    float* zd    = (float*)(W + 6400000);            // NN*16 f = 6,400,000 B
    float* dis   = (float*)(W + 12800000);           // NN f
    int*   bsrc  = (int*)  (W + 13200000);           // NE i   = 6,400,000 B
    unsigned char* bdst8 = (unsigned char*)(W + 19600000);  // NE u8 = 1,600,000 B
    int*   bcnt  = (int*)  (W + 21200064);           // NB
    int*   bptr  = (int*)  (W + 21203264);           // NB+1
    int*   bcur  = (int*)  (W + 21206464);           // NB
    float* W12   = (float*)(W + 21209664);           // 640 f
    float* c1    = (float*)(W + 21212288);           // 10 f

    k_small    <<<1, 256, 0, stream>>>(W1, W2, b1, W12, c1);
    k_bzero    <<<1, 1024, 0, stream>>>(bcnt);
    k_b_count  <<<NCB, 256, 0, stream>>>(dst, bcnt);
    k_b_scan   <<<1, 1024, 0, stream>>>(bcnt, bptr, bcur);
    k_b_scatter<<<NCB, 256, 0, stream>>>(src, dst, bcur, bsrc, bdst8);
    k_deg      <<<NB, 256, 0, stream>>>(bdst8, bptr, dis);
    k_proj     <<<(NN + 63) / 64, 256, 0, stream>>>(x, W12, dis, yd);
    k_agg1     <<<NB, AGG_THREADS, 0, stream>>>(yd, dis, bptr, bsrc, bdst8, zd);
    k_agg2     <<<NB, AGG_THREADS, 0, stream>>>(zd, dis, bptr, bsrc, bdst8, c1, b2, out);
}

// Round 6
// 150.366 us; speedup vs baseline: 3.0304x; 3.0049x over previous
//
#include <hip/hip_runtime.h>

// SimpleGNN 2-layer GCN, linear collapse:
//   out = N^2 x W12 + (N 1) c1^T + 1 b2^T,   N = D^-1/2 (A+I) D^-1/2
//   W12 = W1@W2 (64x10), c1 = b1@W2.
//
// Pipeline:
//   1. bucket edges by dst>>7 (contiguous global writes, no write-amp)
//   2. per-bucket 128-way counting sort in LDS -> full dst-sorted CSR
//      (rowptr, ssrc) + dis = rsqrt(deg+1)
//   3. yd[n] = [dis*(x@W12) (10ch), dis, 0...]  (16-float row = 1 line)
//   4/5. two per-node gather passes (register acc, 4-deep unroll):
//      zd[n][c<10] = dis^2*(yd[n][c]+sum yd[s][c]); zd[n][10] = dis*(...)
//      out[n][c]   = dis*(zd[n][c]+sum zd[s][c]) + zd[n][10]*c1[c] + b2[c]

#define NN 100000
#define NE 1600000
#define NPB 128            // nodes per bucket
#define NB 782             // ceil(NN/NPB)
#define CHUNK 8192         // edges per bucketing block
#define NCB 196            // ceil(NE/CHUNK)

__global__ void k_bzero(int* __restrict__ bcnt) {
    int t = threadIdx.x;
    if (t < NB) bcnt[t] = 0;
}

__global__ __launch_bounds__(256) void k_b_count(const int* __restrict__ dst,
                                                 int* __restrict__ bcnt) {
    __shared__ int h[NB];
    for (int i = threadIdx.x; i < NB; i += 256) h[i] = 0;
    __syncthreads();
    int e0 = blockIdx.x * CHUNK, e1 = min(e0 + CHUNK, NE);
    for (int e = e0 + threadIdx.x; e < e1; e += 256)
        atomicAdd(&h[dst[e] >> 7], 1);
    __syncthreads();
    for (int i = threadIdx.x; i < NB; i += 256)
        if (h[i]) atomicAdd(&bcnt[i], h[i]);
}

__global__ __launch_bounds__(1024) void k_b_scan(const int* __restrict__ bcnt,
                                                 int* __restrict__ bptr,
                                                 int* __restrict__ bcur) {
    __shared__ int sc[1024];
    int t = threadIdx.x;
    int v = (t < NB) ? bcnt[t] : 0;
    sc[t] = v; __syncthreads();
    for (int off = 1; off < 1024; off <<= 1) {
        int a = (t >= off) ? sc[t - off] : 0;
        __syncthreads();
        sc[t] += a;
        __syncthreads();
    }
    if (t < NB) { int e = sc[t] - v; bptr[t] = e; bcur[t] = e; }
    if (t == 0) bptr[NB] = NE;
}

__global__ __launch_bounds__(256) void k_b_scatter(const int* __restrict__ src,
                                                   const int* __restrict__ dst,
                                                   int* __restrict__ bcur,
                                                   int* __restrict__ bsrc,
                                                   unsigned char* __restrict__ bdst8) {
    __shared__ int h[NB];
    __shared__ int cur[NB];
    for (int i = threadIdx.x; i < NB; i += 256) h[i] = 0;
    __syncthreads();
    int e0 = blockIdx.x * CHUNK, e1 = min(e0 + CHUNK, NE);
    for (int e = e0 + threadIdx.x; e < e1; e += 256)
        atomicAdd(&h[dst[e] >> 7], 1);
    __syncthreads();
    for (int i = threadIdx.x; i < NB; i += 256)
        if (h[i]) cur[i] = atomicAdd(&bcur[i], h[i]);
    __syncthreads();
    for (int e = e0 + threadIdx.x; e < e1; e += 256) {
        int d = dst[e];
        int b = d >> 7;
        int p = atomicAdd(&cur[b], 1);
        bsrc[p] = src[e];
        bdst8[p] = (unsigned char)(d & 127);
    }
}

// Per-bucket 128-way counting sort in LDS: emits dst-sorted CSR + dis.
__global__ __launch_bounds__(256) void k_sort(const int* __restrict__ bptr,
                                              const int* __restrict__ bsrc,
                                              const unsigned char* __restrict__ bdst8,
                                              int* __restrict__ rowptr,
                                              int* __restrict__ ssrc,
                                              float* __restrict__ dis) {
    __shared__ int cnt[NPB];
    __shared__ int pre[256];
    __shared__ int cur[NPB];
    int b = blockIdx.x, t = threadIdx.x, base = b * NPB;
    int p0 = bptr[b], p1 = bptr[b + 1];
    if (t < NPB) cnt[t] = 0;
    __syncthreads();
    for (int j = p0 + t; j < p1; j += 256)
        atomicAdd(&cnt[bdst8[j]], 1);
    __syncthreads();
    // inclusive scan over 128 counts (Hillis-Steele, all threads in barriers)
    pre[t] = (t < NPB) ? cnt[t] : 0;
    __syncthreads();
    for (int off = 1; off < NPB; off <<= 1) {
        int a = (t >= off) ? pre[t - off] : 0;
        __syncthreads();
        pre[t] += a;
        __syncthreads();
    }
    if (t < NPB) {
        int exc = p0 + pre[t] - cnt[t];
        cur[t] = exc;
        int n = base + t;
        if (n < NN) {
            rowptr[n] = exc;
            dis[n] = rsqrtf((float)cnt[t] + 1.0f);
        }
    }
    if (b == NB - 1 && t == 0) rowptr[NN] = NE;
    __syncthreads();
    for (int j = p0 + t; j < p1; j += 256) {
        int d = bdst8[j];
        int pos = atomicAdd(&cur[d], 1);
        ssrc[pos] = bsrc[j];
    }
}

// W12 = W1 @ W2 ; c1 = b1 @ W2. One block.
__global__ __launch_bounds__(256) void k_small(const float* __restrict__ W1,
                                               const float* __restrict__ W2,
                                               const float* __restrict__ b1,
                                               float* __restrict__ W12,
                                               float* __restrict__ c1) {
    int t = threadIdx.x;
    for (int o = t; o < 640; o += 256) {
        int k = o / 10, c = o - k * 10;
        float acc = 0.f;
        #pragma unroll
        for (int m = 0; m < 64; ++m) acc = fmaf(W1[k * 64 + m], W2[m * 10 + c], acc);
        W12[o] = acc;
    }
    if (t < 10) {
        float acc = 0.f;
        #pragma unroll
        for (int m = 0; m < 64; ++m) acc = fmaf(b1[m], W2[m * 10 + t], acc);
        c1[t] = acc;
    }
}

// yd[r] = [dis[r]*(x[r]@W12) (c<10), dis[r], zeros]; row stride 16 floats.
__global__ __launch_bounds__(256) void k_proj(const float* __restrict__ x,
                                              const float* __restrict__ W12,
                                              const float* __restrict__ dis,
                                              float* __restrict__ yd) {
    __shared__ float Wl[640];
    __shared__ float tile[64][65];
    __shared__ float ot[64][16];
    for (int i = threadIdx.x; i < 640; i += 256) Wl[i] = W12[i];
    int base = blockIdx.x * 64;
    int nrows = min(64, NN - base);
    for (int i = threadIdx.x; i < nrows * 64; i += 256) {
        int r = i >> 6, k = i & 63;
        tile[r][k] = x[(base + r) * 64 + k];
    }
    for (int i = threadIdx.x; i < 64 * 16; i += 256) ((float*)ot)[i] = 0.f;
    __syncthreads();
    for (int o = threadIdx.x; o < nrows * 10; o += 256) {
        int r = o / 10, c = o - r * 10;
        float acc = 0.f;
        #pragma unroll
        for (int k = 0; k < 64; ++k) acc = fmaf(tile[r][k], Wl[k * 10 + c], acc);
        ot[r][c] = dis[base + r] * acc;
    }
    if (threadIdx.x < nrows) ot[threadIdx.x][10] = dis[base + threadIdx.x];
    __syncthreads();
    for (int i = threadIdx.x; i < nrows * 16; i += 256)
        yd[base * 16 + i] = ((const float*)ot)[i];
}

// Pass 1: per-node gather, register acc, 4-deep unroll. Grid exact NN*16.
__global__ __launch_bounds__(256) void k_aggA(const float* __restrict__ yd,
                                              const float* __restrict__ dis,
                                              const int* __restrict__ rowptr,
                                              const int* __restrict__ ssrc,
                                              float* __restrict__ zd) {
    int t = blockIdx.x * blockDim.x + threadIdx.x;
    int n = t >> 4, lane = t & 15;
    int beg = rowptr[n], end = rowptr[n + 1];
    float a0 = yd[n * 16 + lane];   // self term (dis folded in)
    float a1 = 0.f, a2 = 0.f, a3 = 0.f;
    int j = beg;
    for (; j + 3 < end; j += 4) {
        int s0 = ssrc[j], s1 = ssrc[j + 1], s2 = ssrc[j + 2], s3 = ssrc[j + 3];
        a0 += yd[s0 * 16 + lane];
        a1 += yd[s1 * 16 + lane];
        a2 += yd[s2 * 16 + lane];
        a3 += yd[s3 * 16 + lane];
    }
    for (; j < end; ++j) a0 += yd[ssrc[j] * 16 + lane];
    float d = dis[n];
    float scale = (lane == 10) ? d : d * d;
    zd[n * 16 + lane] = (lane < 11) ? scale * ((a0 + a1) + (a2 + a3)) : 0.f;
}

// Pass 2: out[n][c] = dis*(zd self+nbrs) + n1*c1[c] + b2[c].
__global__ __launch_bounds__(256) void k_aggB(const float* __restrict__ zd,
                                              const float* __restrict__ dis,
                                              const int* __restrict__ rowptr,
                                              const int* __restrict__ ssrc,
                                              const float* __restrict__ c1,
                                              const float* __restrict__ b2,
                                              float* __restrict__ out) {
    int t = blockIdx.x * blockDim.x + threadIdx.x;
    int n = t >> 4, lane = t & 15;
    int beg = rowptr[n], end = rowptr[n + 1];
    float a0 = zd[n * 16 + lane];   // self term
    float a1 = 0.f, a2 = 0.f, a3 = 0.f;
    int j = beg;
    for (; j + 3 < end; j += 4) {
        int s0 = ssrc[j], s1 = ssrc[j + 1], s2 = ssrc[j + 2], s3 = ssrc[j + 3];
        a0 += zd[s0 * 16 + lane];
        a1 += zd[s1 * 16 + lane];
        a2 += zd[s2 * 16 + lane];
        a3 += zd[s3 * 16 + lane];
    }
    for (; j < end; ++j) a0 += zd[ssrc[j] * 16 + lane];
    if (lane < 10) {
        float n1 = zd[n * 16 + 10];
        float acc = (a0 + a1) + (a2 + a3);
        out[n * 10 + lane] = fmaf(dis[n], acc, fmaf(n1, c1[lane], b2[lane]));
    }
}

extern "C" void kernel_launch(void* const* d_in, const int* in_sizes, int n_in,
                              void* d_out, int out_size, void* d_ws, size_t ws_size,
                              hipStream_t stream) {
    const float* x  = (const float*)d_in[0];
    const float* W1 = (const float*)d_in[1];
    const float* b1 = (const float*)d_in[2];
    const float* W2 = (const float*)d_in[3];
    const float* b2 = (const float*)d_in[4];
    const int* edge = (const int*)d_in[5];   // [2, NE]: src row then dst row
    const int* src = edge;
    const int* dst = edge + NE;
    float* out = (float*)d_out;

    // Workspace layout (64B-aligned), total ~28.0 MB:
    char* W = (char*)d_ws;
    float* yd    = (float*)(W);                      // NN*16 f = 6,400,000 B
    float* zd    = (float*)(W + 6400000);            // NN*16 f = 6,400,000 B
    float* dis   = (float*)(W + 12800000);           // NN f
    int*   bsrc  = (int*)  (W + 13200000);           // NE i   = 6,400,000 B
    unsigned char* bdst8 = (unsigned char*)(W + 19600000);  // NE u8 = 1,600,000 B
    int*   ssrc  = (int*)  (W + 21200000);           // NE i   = 6,400,000 B
    int*   rowptr= (int*)  (W + 27600000);           // NN+1
    int*   bcnt  = (int*)  (W + 28000064);           // NB
    int*   bptr  = (int*)  (W + 28003264);           // NB+1
    int*   bcur  = (int*)  (W + 28006464);           // NB
    float* W12   = (float*)(W + 28009664);           // 640 f
    float* c1    = (float*)(W + 28012288);           // 10 f

    k_small    <<<1, 256, 0, stream>>>(W1, W2, b1, W12, c1);
    k_bzero    <<<1, 1024, 0, stream>>>(bcnt);
    k_b_count  <<<NCB, 256, 0, stream>>>(dst, bcnt);
    k_b_scan   <<<1, 1024, 0, stream>>>(bcnt, bptr, bcur);
    k_b_scatter<<<NCB, 256, 0, stream>>>(src, dst, bcur, bsrc, bdst8);
    k_sort     <<<NB, 256, 0, stream>>>(bptr, bsrc, bdst8, rowptr, ssrc, dis);
    k_proj     <<<(NN + 63) / 64, 256, 0, stream>>>(x, W12, dis, yd);
    k_aggA     <<<(NN * 16) / 256, 256, 0, stream>>>(yd, dis, rowptr, ssrc, zd);
    k_aggB     <<<(NN * 16) / 256, 256, 0, stream>>>(zd, dis, rowptr, ssrc, c1, b2, out);
}

// Round 7
// 121.078 us; speedup vs baseline: 3.7634x; 1.2419x over previous
//
#include <hip/hip_runtime.h>

// SimpleGNN 2-layer GCN, linear collapse:
//   out = N^2 x W12 + (N 1) c1^T + 1 b2^T,   N = D^-1/2 (A+I) D^-1/2
//   W12 = W1@W2 (64x10), c1 = b1@W2.
//
// Build (no global coordination, write-amp 1):
//   k_part: each 4096-edge chunk counting-sorts by bucket (dst>>8) in LDS,
//           writes packed (src<<8 | dst&255) to its PRIVATE arena slice
//           [e0,e1) + a segment-offset row scanT[c][0..NB].
//   k_sort: one block per 256-node bucket gathers its NCB segments into LDS,
//           256-way counting sort -> ssrc (per-bucket arena slot, cap MAXB),
//           rowbe[n] = (beg,end), dis = rsqrt(deg+1).
// Compute:
//   k_proj: yd[n] = [dis*(x@W12) (10ch), dis, 0...] (16-float line)
//   k_aggA: zd[n][c<10] = dis^2*(yd[n][c]+sum_src yd[s][c]); ch10 = dis*(...)
//   k_aggB: out[n][c] = dis*(zd self+nbrs) + zd[n][10]*c1[c] + b2[c]

#define NN 100000
#define NE 1600000
#define NPB 256            // nodes per bucket
#define NB 391             // ceil(NN/NPB); NB*NPB = 100096
#define CHUNK 4096         // edges per partition block
#define NCB 391            // ceil(NE/CHUNK)
#define MAXB 5120          // per-bucket edge cap (mean 4096, +16 sigma)

// W12 = W1 @ W2 ; c1 = b1 @ W2. One block.
__global__ __launch_bounds__(256) void k_small(const float* __restrict__ W1,
                                               const float* __restrict__ W2,
                                               const float* __restrict__ b1,
                                               float* __restrict__ W12,
                                               float* __restrict__ c1) {
    int t = threadIdx.x;
    for (int o = t; o < 640; o += 256) {
        int k = o / 10, c = o - k * 10;
        float acc = 0.f;
        #pragma unroll
        for (int m = 0; m < 64; ++m) acc = fmaf(W1[k * 64 + m], W2[m * 10 + c], acc);
        W12[o] = acc;
    }
    if (t < 10) {
        float acc = 0.f;
        #pragma unroll
        for (int m = 0; m < 64; ++m) acc = fmaf(b1[m], W2[m * 10 + t], acc);
        c1[t] = acc;
    }
}

// Partition: per-chunk LDS counting sort by bucket, private-arena writeout.
__global__ __launch_bounds__(256) void k_part(const int* __restrict__ src,
                                              const int* __restrict__ dst,
                                              int* __restrict__ packed,
                                              int* __restrict__ scanT) {
    __shared__ int hist[NB];
    __shared__ int sc[256];
    __shared__ int cur[NB];
    __shared__ int buf[CHUNK];
    int c = blockIdx.x, t = threadIdx.x;
    int e0 = c * CHUNK, e1 = min(e0 + CHUNK, NE);
    int n = e1 - e0;
    for (int i = t; i < NB; i += 256) hist[i] = 0;
    __syncthreads();
    int pk[16], bk[16];
    #pragma unroll
    for (int k = 0; k < 16; ++k) {
        int e = e0 + t + k * 256;
        if (e < e1) {
            int s = src[e], d = dst[e];
            pk[k] = (s << 8) | (d & 255);
            bk[k] = d >> 8;
            atomicAdd(&hist[bk[k]], 1);
        } else bk[k] = -1;
    }
    __syncthreads();
    // exclusive scan of hist[0..NB-1] via pair-compaction into 256-wide scan
    int i0 = 2 * t, i1 = 2 * t + 1;
    int h0 = (i0 < NB) ? hist[i0] : 0;
    int h1 = (i1 < NB) ? hist[i1] : 0;
    int ps = h0 + h1;
    sc[t] = ps; __syncthreads();
    for (int off = 1; off < 256; off <<= 1) {
        int a = (t >= off) ? sc[t - off] : 0;
        __syncthreads(); sc[t] += a; __syncthreads();
    }
    int exc = sc[t] - ps;
    if (i0 < NB) cur[i0] = exc;
    if (i1 < NB) cur[i1] = exc + h0;
    __syncthreads();
    // segment-offset row (absolute arena indices), before cur is consumed
    for (int b = t; b < NB; b += 256) scanT[c * (NB + 1) + b] = e0 + cur[b];
    if (t == 0) scanT[c * (NB + 1) + NB] = e0 + n;
    __syncthreads();
    #pragma unroll
    for (int k = 0; k < 16; ++k) {
        if (bk[k] >= 0) {
            int pos = atomicAdd(&cur[bk[k]], 1);
            buf[pos] = pk[k];
        }
    }
    __syncthreads();
    for (int i = t; i < n; i += 256) packed[e0 + i] = buf[i];
}

// Per-bucket: gather NCB segments -> LDS stage -> 256-way counting sort ->
// ssrc window [b*MAXB, ...), rowbe = (beg,end), dis.
__global__ __launch_bounds__(256) void k_sort(const int* __restrict__ packed,
                                              const int* __restrict__ scanT,
                                              int* __restrict__ ssrc,
                                              int2* __restrict__ rowbe,
                                              float* __restrict__ dis) {
    __shared__ int stage[MAXB];
    __shared__ int cnt[NPB];
    __shared__ int sc[256];
    __shared__ int cur[NPB];
    __shared__ int stot;
    int b = blockIdx.x, t = threadIdx.x;
    cnt[t] = 0;
    if (t == 0) stot = 0;
    __syncthreads();
    for (int c = t; c < NCB; c += 256) {
        int s0 = scanT[c * (NB + 1) + b];
        int s1 = scanT[c * (NB + 1) + b + 1];
        int m = s1 - s0;
        if (m > 0) {
            int base = atomicAdd(&stot, m);
            for (int j = 0; j < m; ++j) {
                int p = packed[s0 + j];
                if (base + j < MAXB) stage[base + j] = p;
                atomicAdd(&cnt[p & 255], 1);
            }
        }
    }
    __syncthreads();
    int T = min(stot, MAXB);
    int h = cnt[t];
    sc[t] = h; __syncthreads();
    for (int off = 1; off < 256; off <<= 1) {
        int a = (t >= off) ? sc[t - off] : 0;
        __syncthreads(); sc[t] += a; __syncthreads();
    }
    int exc = sc[t] - h;
    int wbase = b * MAXB;
    int nidx = b * NPB + t;
    if (nidx < NN) {
        rowbe[nidx] = make_int2(wbase + exc, wbase + exc + h);
        dis[nidx] = rsqrtf((float)h + 1.0f);
    }
    cur[t] = wbase + exc;
    __syncthreads();
    for (int i = t; i < T; i += 256) {
        int p = stage[i];
        int pos = atomicAdd(&cur[p & 255], 1);
        ssrc[pos] = p >> 8;
    }
}

// yd[r] = [dis[r]*(x[r]@W12) (c<10), dis[r], zeros]; row stride 16 floats.
__global__ __launch_bounds__(256) void k_proj(const float* __restrict__ x,
                                              const float* __restrict__ W12,
                                              const float* __restrict__ dis,
                                              float* __restrict__ yd) {
    __shared__ float Wl[640];
    __shared__ float tile[64][65];
    __shared__ float ot[64][16];
    for (int i = threadIdx.x; i < 640; i += 256) Wl[i] = W12[i];
    int base = blockIdx.x * 64;
    int nrows = min(64, NN - base);
    for (int i = threadIdx.x; i < nrows * 16; i += 256) {
        int r = i >> 4, q = i & 15;
        float4 v = *(const float4*)&x[(base + r) * 64 + q * 4];
        tile[r][q * 4 + 0] = v.x;
        tile[r][q * 4 + 1] = v.y;
        tile[r][q * 4 + 2] = v.z;
        tile[r][q * 4 + 3] = v.w;
    }
    for (int i = threadIdx.x; i < 64 * 16; i += 256) ((float*)ot)[i] = 0.f;
    __syncthreads();
    for (int o = threadIdx.x; o < nrows * 10; o += 256) {
        int r = o / 10, c = o - r * 10;
        float acc = 0.f;
        #pragma unroll
        for (int k = 0; k < 64; ++k) acc = fmaf(tile[r][k], Wl[k * 10 + c], acc);
        ot[r][c] = dis[base + r] * acc;
    }
    if (threadIdx.x < nrows) ot[threadIdx.x][10] = dis[base + threadIdx.x];
    __syncthreads();
    for (int i = threadIdx.x; i < nrows * 16; i += 256)
        yd[base * 16 + i] = ((const float*)ot)[i];
}

// Pass 1: per-node gather, register acc, 4-deep unroll. Grid exact NN*16.
__global__ __launch_bounds__(256) void k_aggA(const float* __restrict__ yd,
                                              const float* __restrict__ dis,
                                              const int2* __restrict__ rowbe,
                                              const int* __restrict__ ssrc,
                                              float* __restrict__ zd) {
    int t = blockIdx.x * blockDim.x + threadIdx.x;
    int n = t >> 4, lane = t & 15;
    int2 be = rowbe[n];
    float a0 = yd[n * 16 + lane];   // self term (dis folded in)
    float a1 = 0.f, a2 = 0.f, a3 = 0.f;
    int j = be.x;
    for (; j + 3 < be.y; j += 4) {
        int s0 = ssrc[j], s1 = ssrc[j + 1], s2 = ssrc[j + 2], s3 = ssrc[j + 3];
        a0 += yd[s0 * 16 + lane];
        a1 += yd[s1 * 16 + lane];
        a2 += yd[s2 * 16 + lane];
        a3 += yd[s3 * 16 + lane];
    }
    for (; j < be.y; ++j) a0 += yd[ssrc[j] * 16 + lane];
    float d = dis[n];
    float scale = (lane == 10) ? d : d * d;
    zd[n * 16 + lane] = (lane < 11) ? scale * ((a0 + a1) + (a2 + a3)) : 0.f;
}

// Pass 2: out[n][c] = dis*(zd self+nbrs) + n1*c1[c] + b2[c].
__global__ __launch_bounds__(256) void k_aggB(const float* __restrict__ zd,
                                              const float* __restrict__ dis,
                                              const int2* __restrict__ rowbe,
                                              const int* __restrict__ ssrc,
                                              const float* __restrict__ c1,
                                              const float* __restrict__ b2,
                                              float* __restrict__ out) {
    int t = blockIdx.x * blockDim.x + threadIdx.x;
    int n = t >> 4, lane = t & 15;
    int2 be = rowbe[n];
    float a0 = zd[n * 16 + lane];   // self term
    float a1 = 0.f, a2 = 0.f, a3 = 0.f;
    int j = be.x;
    for (; j + 3 < be.y; j += 4) {
        int s0 = ssrc[j], s1 = ssrc[j + 1], s2 = ssrc[j + 2], s3 = ssrc[j + 3];
        a0 += zd[s0 * 16 + lane];
        a1 += zd[s1 * 16 + lane];
        a2 += zd[s2 * 16 + lane];
        a3 += zd[s3 * 16 + lane];
    }
    for (; j < be.y; ++j) a0 += zd[ssrc[j] * 16 + lane];
    if (lane < 10) {
        float n1 = zd[n * 16 + 10];
        float acc = (a0 + a1) + (a2 + a3);
        out[n * 10 + lane] = fmaf(dis[n], acc, fmaf(n1, c1[lane], b2[lane]));
    }
}

extern "C" void kernel_launch(void* const* d_in, const int* in_sizes, int n_in,
                              void* d_out, int out_size, void* d_ws, size_t ws_size,
                              hipStream_t stream) {
    const float* x  = (const float*)d_in[0];
    const float* W1 = (const float*)d_in[1];
    const float* b1 = (const float*)d_in[2];
    const float* W2 = (const float*)d_in[3];
    const float* b2 = (const float*)d_in[4];
    const int* edge = (const int*)d_in[5];   // [2, NE]: src row then dst row
    const int* src = edge;
    const int* dst = edge + NE;
    float* out = (float*)d_out;

    // Workspace layout (64B-aligned), total ~29.0 MB:
    char* W = (char*)d_ws;
    float* yd     = (float*)(W);                   // NN*16 f     = 6,400,000 B
    float* zd     = (float*)(W + 6400000);         // NN*16 f     = 6,400,000 B
    float* dis    = (float*)(W + 12800000);        // NN f        =   400,000 B
    int*   packed = (int*)  (W + 13200000);        // NE i        = 6,400,000 B
    int*   scanT  = (int*)  (W + 19600000);        // NCB*(NB+1)  =   613,088 B
    int*   ssrc   = (int*)  (W + 20213120);        // NB*MAXB i   = 8,007,680 B
    int2*  rowbe  = (int2*) (W + 28220800);        // NN int2     =   800,000 B
    float* W12    = (float*)(W + 29020800);        // 640 f
    float* c1     = (float*)(W + 29023360);        // 10 f

    k_small<<<1, 256, 0, stream>>>(W1, W2, b1, W12, c1);
    k_part <<<NCB, 256, 0, stream>>>(src, dst, packed, scanT);
    k_sort <<<NB, 256, 0, stream>>>(packed, scanT, ssrc, rowbe, dis);
    k_proj <<<(NN + 63) / 64, 256, 0, stream>>>(x, W12, dis, yd);
    k_aggA <<<(NN * 16) / 256, 256, 0, stream>>>(yd, dis, rowbe, ssrc, zd);
    k_aggB <<<(NN * 16) / 256, 256, 0, stream>>>(zd, dis, rowbe, ssrc, c1, b2, out);
}

// Round 8
// 114.479 us; speedup vs baseline: 3.9804x; 1.0576x over previous
//
#include <hip/hip_runtime.h>

// SimpleGNN 2-layer GCN, linear collapse:
//   out = N^2 x W12 + (N 1) c1^T + 1 b2^T,   N = D^-1/2 (A+I) D^-1/2
//   W12 = W1@W2 (64x10), c1 = b1@W2.
//
// Build (no global coordination, write-amp 1):
//   k_part: each 4096-edge chunk counting-sorts by bucket (dst>>8) in LDS,
//           writes packed (src<<8 | dst&255) to its PRIVATE arena slice
//           [e0,e1) + a segment-offset row scanT[c][0..NB].
//   k_sort: one block per 256-node bucket gathers its NCB segments into LDS,
//           256-way counting sort -> ssrc (per-bucket arena slot, cap MAXB),
//           rowbe[n] = (beg,end), dis = rsqrt(deg+1).
// Compute:
//   k_proj: yd[n] = [dis*(x@W12) (10ch), dis, 0] (16-float row, 12 written)
//   k_aggA/k_aggB: 4 lanes/node, lane q<3 gathers float4 yd[s*16+q*4]
//   (2 VMEM instr per 16 edges vs 17 for the 16-lane scalar form).

#define NN 100000
#define NE 1600000
#define NPB 256            // nodes per bucket
#define NB 391             // ceil(NN/NPB); NB*NPB = 100096
#define CHUNK 4096         // edges per partition block
#define NCB 391            // ceil(NE/CHUNK)
#define MAXB 5120          // per-bucket edge cap (mean 4096, +16 sigma)

// W12 = W1 @ W2 ; c1 = b1 @ W2. One block.
__global__ __launch_bounds__(256) void k_small(const float* __restrict__ W1,
                                               const float* __restrict__ W2,
                                               const float* __restrict__ b1,
                                               float* __restrict__ W12,
                                               float* __restrict__ c1) {
    int t = threadIdx.x;
    for (int o = t; o < 640; o += 256) {
        int k = o / 10, c = o - k * 10;
        float acc = 0.f;
        #pragma unroll
        for (int m = 0; m < 64; ++m) acc = fmaf(W1[k * 64 + m], W2[m * 10 + c], acc);
        W12[o] = acc;
    }
    if (t < 10) {
        float acc = 0.f;
        #pragma unroll
        for (int m = 0; m < 64; ++m) acc = fmaf(b1[m], W2[m * 10 + t], acc);
        c1[t] = acc;
    }
}

// Partition: per-chunk LDS counting sort by bucket, private-arena writeout.
__global__ __launch_bounds__(256) void k_part(const int* __restrict__ src,
                                              const int* __restrict__ dst,
                                              int* __restrict__ packed,
                                              int* __restrict__ scanT) {
    __shared__ int hist[NB];
    __shared__ int sc[256];
    __shared__ int cur[NB];
    __shared__ int buf[CHUNK];
    int c = blockIdx.x, t = threadIdx.x;
    int e0 = c * CHUNK, e1 = min(e0 + CHUNK, NE);
    int n = e1 - e0;
    for (int i = t; i < NB; i += 256) hist[i] = 0;
    __syncthreads();
    int pk[16], bk[16];
    #pragma unroll
    for (int k = 0; k < 16; ++k) {
        int e = e0 + t + k * 256;
        if (e < e1) {
            int s = src[e], d = dst[e];
            pk[k] = (s << 8) | (d & 255);
            bk[k] = d >> 8;
            atomicAdd(&hist[bk[k]], 1);
        } else bk[k] = -1;
    }
    __syncthreads();
    // exclusive scan of hist[0..NB-1] via pair-compaction into 256-wide scan
    int i0 = 2 * t, i1 = 2 * t + 1;
    int h0 = (i0 < NB) ? hist[i0] : 0;
    int h1 = (i1 < NB) ? hist[i1] : 0;
    int ps = h0 + h1;
    sc[t] = ps; __syncthreads();
    for (int off = 1; off < 256; off <<= 1) {
        int a = (t >= off) ? sc[t - off] : 0;
        __syncthreads(); sc[t] += a; __syncthreads();
    }
    int exc = sc[t] - ps;
    if (i0 < NB) cur[i0] = exc;
    if (i1 < NB) cur[i1] = exc + h0;
    __syncthreads();
    // segment-offset row (absolute arena indices), before cur is consumed
    for (int b = t; b < NB; b += 256) scanT[c * (NB + 1) + b] = e0 + cur[b];
    if (t == 0) scanT[c * (NB + 1) + NB] = e0 + n;
    __syncthreads();
    #pragma unroll
    for (int k = 0; k < 16; ++k) {
        if (bk[k] >= 0) {
            int pos = atomicAdd(&cur[bk[k]], 1);
            buf[pos] = pk[k];
        }
    }
    __syncthreads();
    for (int i = t; i < n; i += 256) packed[e0 + i] = buf[i];
}

// Per-bucket: gather NCB segments -> LDS stage -> 256-way counting sort ->
// ssrc window [b*MAXB, ...), rowbe = (beg,end), dis.
__global__ __launch_bounds__(256) void k_sort(const int* __restrict__ packed,
                                              const int* __restrict__ scanT,
                                              int* __restrict__ ssrc,
                                              int2* __restrict__ rowbe,
                                              float* __restrict__ dis) {
    __shared__ int stage[MAXB];
    __shared__ int cnt[NPB];
    __shared__ int sc[256];
    __shared__ int cur[NPB];
    __shared__ int stot;
    int b = blockIdx.x, t = threadIdx.x;
    cnt[t] = 0;
    if (t == 0) stot = 0;
    __syncthreads();
    for (int c = t; c < NCB; c += 256) {
        int s0 = scanT[c * (NB + 1) + b];
        int s1 = scanT[c * (NB + 1) + b + 1];
        int m = s1 - s0;
        if (m > 0) {
            int base = atomicAdd(&stot, m);
            for (int j = 0; j < m; ++j) {
                int p = packed[s0 + j];
                if (base + j < MAXB) stage[base + j] = p;
                atomicAdd(&cnt[p & 255], 1);
            }
        }
    }
    __syncthreads();
    int T = min(stot, MAXB);
    int h = cnt[t];
    sc[t] = h; __syncthreads();
    for (int off = 1; off < 256; off <<= 1) {
        int a = (t >= off) ? sc[t - off] : 0;
        __syncthreads(); sc[t] += a; __syncthreads();
    }
    int exc = sc[t] - h;
    int wbase = b * MAXB;
    int nidx = b * NPB + t;
    if (nidx < NN) {
        rowbe[nidx] = make_int2(wbase + exc, wbase + exc + h);
        dis[nidx] = rsqrtf((float)h + 1.0f);
    }
    cur[t] = wbase + exc;
    __syncthreads();
    for (int i = t; i < T; i += 256) {
        int p = stage[i];
        int pos = atomicAdd(&cur[p & 255], 1);
        ssrc[pos] = p >> 8;
    }
}

// yd[r] = [dis[r]*(x[r]@W12) (c<10), dis[r], 0]; row stride 16, 12 written.
__global__ __launch_bounds__(256) void k_proj(const float* __restrict__ x,
                                              const float* __restrict__ W12,
                                              const float* __restrict__ dis,
                                              float* __restrict__ yd) {
    __shared__ float Wl[640];
    __shared__ float tile[64][65];
    __shared__ float ot[64][16];
    for (int i = threadIdx.x; i < 640; i += 256) Wl[i] = W12[i];
    int base = blockIdx.x * 64;
    int nrows = min(64, NN - base);
    for (int i = threadIdx.x; i < nrows * 16; i += 256) {
        int r = i >> 4, q = i & 15;
        float4 v = *(const float4*)&x[(base + r) * 64 + q * 4];
        tile[r][q * 4 + 0] = v.x;
        tile[r][q * 4 + 1] = v.y;
        tile[r][q * 4 + 2] = v.z;
        tile[r][q * 4 + 3] = v.w;
    }
    for (int i = threadIdx.x; i < 64 * 16; i += 256) ((float*)ot)[i] = 0.f;
    __syncthreads();
    for (int o = threadIdx.x; o < nrows * 10; o += 256) {
        int r = o / 10, c = o - r * 10;
        float acc = 0.f;
        #pragma unroll
        for (int k = 0; k < 64; ++k) acc = fmaf(tile[r][k], Wl[k * 10 + c], acc);
        ot[r][c] = dis[base + r] * acc;
    }
    if (threadIdx.x < nrows) ot[threadIdx.x][10] = dis[base + threadIdx.x];
    __syncthreads();
    for (int i = threadIdx.x; i < nrows * 4; i += 256) {
        int r = i >> 2, q = i & 3;
        if (q < 3)
            *(float4*)&yd[(base + r) * 16 + q * 4] = *(const float4*)&ot[r][q * 4];
    }
}

// Pass 1: 4 lanes/node, lane q<3 gathers float4; 4-deep unroll.
// zd[n][c<10] = dis^2*(yd self+nbrs); zd[n][10] = dis*(...); zd[n][11] = 0.
__global__ __launch_bounds__(256) void k_aggA(const float* __restrict__ yd,
                                              const float* __restrict__ dis,
                                              const int2* __restrict__ rowbe,
                                              const int* __restrict__ ssrc,
                                              float* __restrict__ zd) {
    int t = blockIdx.x * blockDim.x + threadIdx.x;
    int n = t >> 2, q = t & 3;
    if (n >= NN) return;
    int2 be = rowbe[n];
    const bool act = (q < 3);
    float4 a0 = make_float4(0.f, 0.f, 0.f, 0.f), a1 = a0, a2 = a0, a3 = a0;
    if (act) a0 = *(const float4*)&yd[n * 16 + q * 4];   // self term
    int j = be.x;
    for (; j + 3 < be.y; j += 4) {
        int s0 = ssrc[j], s1 = ssrc[j + 1], s2 = ssrc[j + 2], s3 = ssrc[j + 3];
        if (act) {
            float4 v0 = *(const float4*)&yd[s0 * 16 + q * 4];
            float4 v1 = *(const float4*)&yd[s1 * 16 + q * 4];
            float4 v2 = *(const float4*)&yd[s2 * 16 + q * 4];
            float4 v3 = *(const float4*)&yd[s3 * 16 + q * 4];
            a0.x += v0.x; a0.y += v0.y; a0.z += v0.z; a0.w += v0.w;
            a1.x += v1.x; a1.y += v1.y; a1.z += v1.z; a1.w += v1.w;
            a2.x += v2.x; a2.y += v2.y; a2.z += v2.z; a2.w += v2.w;
            a3.x += v3.x; a3.y += v3.y; a3.z += v3.z; a3.w += v3.w;
        }
    }
    for (; j < be.y; ++j) {
        int s = ssrc[j];
        if (act) {
            float4 v = *(const float4*)&yd[s * 16 + q * 4];
            a0.x += v.x; a0.y += v.y; a0.z += v.z; a0.w += v.w;
        }
    }
    if (act) {
        float4 s;
        s.x = (a0.x + a1.x) + (a2.x + a3.x);
        s.y = (a0.y + a1.y) + (a2.y + a3.y);
        s.z = (a0.z + a1.z) + (a2.z + a3.z);
        s.w = (a0.w + a1.w) + (a2.w + a3.w);
        float d = dis[n], d2 = d * d;
        if (q < 2) { s.x *= d2; s.y *= d2; s.z *= d2; s.w *= d2; }
        else       { s.x *= d2; s.y *= d2; s.z *= d;  s.w  = 0.f; }
        *(float4*)&zd[n * 16 + q * 4] = s;
    }
}

// Pass 2: out[n][c] = dis*(zd self+nbrs)[c] + zd[n][10]*c1[c] + b2[c].
__global__ __launch_bounds__(256) void k_aggB(const float* __restrict__ zd,
                                              const float* __restrict__ dis,
                                              const int2* __restrict__ rowbe,
                                              const int* __restrict__ ssrc,
                                              const float* __restrict__ c1,
                                              const float* __restrict__ b2,
                                              float* __restrict__ out) {
    int t = blockIdx.x * blockDim.x + threadIdx.x;
    int n = t >> 2, q = t & 3;
    if (n >= NN) return;
    int2 be = rowbe[n];
    const bool act = (q < 3);
    float4 self = make_float4(0.f, 0.f, 0.f, 0.f);
    if (act) self = *(const float4*)&zd[n * 16 + q * 4];
    float4 a0 = self, a1 = make_float4(0.f, 0.f, 0.f, 0.f), a2 = a1, a3 = a1;
    int j = be.x;
    for (; j + 3 < be.y; j += 4) {
        int s0 = ssrc[j], s1 = ssrc[j + 1], s2 = ssrc[j + 2], s3 = ssrc[j + 3];
        if (act) {
            float4 v0 = *(const float4*)&zd[s0 * 16 + q * 4];
            float4 v1 = *(const float4*)&zd[s1 * 16 + q * 4];
            float4 v2 = *(const float4*)&zd[s2 * 16 + q * 4];
            float4 v3 = *(const float4*)&zd[s3 * 16 + q * 4];
            a0.x += v0.x; a0.y += v0.y; a0.z += v0.z; a0.w += v0.w;
            a1.x += v1.x; a1.y += v1.y; a1.z += v1.z; a1.w += v1.w;
            a2.x += v2.x; a2.y += v2.y; a2.z += v2.z; a2.w += v2.w;
            a3.x += v3.x; a3.y += v3.y; a3.z += v3.z; a3.w += v3.w;
        }
    }
    for (; j < be.y; ++j) {
        int s = ssrc[j];
        if (act) {
            float4 v = *(const float4*)&zd[s * 16 + q * 4];
            a0.x += v.x; a0.y += v.y; a0.z += v.z; a0.w += v.w;
        }
    }
    float4 s;
    s.x = (a0.x + a1.x) + (a2.x + a3.x);
    s.y = (a0.y + a1.y) + (a2.y + a3.y);
    s.z = (a0.z + a1.z) + (a2.z + a3.z);
    s.w = (a0.w + a1.w) + (a2.w + a3.w);
    float n1 = __shfl(self.z, 2, 4);   // zd[n][10] from q2's self load
    float d = dis[n];
    if (q == 0) {
        out[n * 10 + 0] = fmaf(d, s.x, fmaf(n1, c1[0], b2[0]));
        out[n * 10 + 1] = fmaf(d, s.y, fmaf(n1, c1[1], b2[1]));
        out[n * 10 + 2] = fmaf(d, s.z, fmaf(n1, c1[2], b2[2]));
        out[n * 10 + 3] = fmaf(d, s.w, fmaf(n1, c1[3], b2[3]));
    } else if (q == 1) {
        out[n * 10 + 4] = fmaf(d, s.x, fmaf(n1, c1[4], b2[4]));
        out[n * 10 + 5] = fmaf(d, s.y, fmaf(n1, c1[5], b2[5]));
        out[n * 10 + 6] = fmaf(d, s.z, fmaf(n1, c1[6], b2[6]));
        out[n * 10 + 7] = fmaf(d, s.w, fmaf(n1, c1[7], b2[7]));
    } else if (q == 2) {
        out[n * 10 + 8] = fmaf(d, s.x, fmaf(n1, c1[8], b2[8]));
        out[n * 10 + 9] = fmaf(d, s.y, fmaf(n1, c1[9], b2[9]));
    }
}

extern "C" void kernel_launch(void* const* d_in, const int* in_sizes, int n_in,
                              void* d_out, int out_size, void* d_ws, size_t ws_size,
                              hipStream_t stream) {
    const float* x  = (const float*)d_in[0];
    const float* W1 = (const float*)d_in[1];
    const float* b1 = (const float*)d_in[2];
    const float* W2 = (const float*)d_in[3];
    const float* b2 = (const float*)d_in[4];
    const int* edge = (const int*)d_in[5];   // [2, NE]: src row then dst row
    const int* src = edge;
    const int* dst = edge + NE;
    float* out = (float*)d_out;

    // Workspace layout (64B-aligned), total ~29.0 MB:
    char* W = (char*)d_ws;
    float* yd     = (float*)(W);                   // NN*16 f     = 6,400,000 B
    float* zd     = (float*)(W + 6400000);         // NN*16 f     = 6,400,000 B
    float* dis    = (float*)(W + 12800000);        // NN f        =   400,000 B
    int*   packed = (int*)  (W + 13200000);        // NE i        = 6,400,000 B
    int*   scanT  = (int*)  (W + 19600000);        // NCB*(NB+1)  =   613,088 B
    int*   ssrc   = (int*)  (W + 20213120);        // NB*MAXB i   = 8,007,680 B
    int2*  rowbe  = (int2*) (W + 28220800);        // NN int2     =   800,000 B
    float* W12    = (float*)(W + 29020800);        // 640 f
    float* c1     = (float*)(W + 29023360);        // 10 f

    k_small<<<1, 256, 0, stream>>>(W1, W2, b1, W12, c1);
    k_part <<<NCB, 256, 0, stream>>>(src, dst, packed, scanT);
    k_sort <<<NB, 256, 0, stream>>>(packed, scanT, ssrc, rowbe, dis);
    k_proj <<<(NN + 63) / 64, 256, 0, stream>>>(x, W12, dis, yd);
    k_aggA <<<(NN * 4 + 255) / 256, 256, 0, stream>>>(yd, dis, rowbe, ssrc, zd);
    k_aggB <<<(NN * 4 + 255) / 256, 256, 0, stream>>>(zd, dis, rowbe, ssrc, c1, b2, out);
}

// Round 9
// 105.495 us; speedup vs baseline: 4.3193x; 1.0852x over previous
//
#include <hip/hip_runtime.h>

// SimpleGNN 2-layer GCN, linear collapse:
//   out = N^2 x W12 + (N 1) c1^T + 1 b2^T,   N = D^-1/2 (A+I) D^-1/2
//   W12 = W1@W2 (64x10), c1 = b1@W2.
//
// 4-kernel pipeline:
//   k_part   : chunk-private LDS counting sort by bucket (dst>>8) -> packed
//              arena + scanT row. Block NCB additionally computes W12/c1.
//   k_sortproj: per 256-node bucket: gather segments -> LDS stage -> 256-way
//              counting sort -> ssrc/rowbe/dis; THEN (reusing the same LDS)
//              project its own 256 rows: yd[n]=[dis*(x@W12),dis,0] (16f row).
//   k_aggA   : 4 lanes/node float4 gather: zd = dis^2*(self+nbrs); ch10=dis*(..)
//   k_aggB   : same over zd; out = dis*(..) + zd[n][10]*c1 + b2.

#define NN 100000
#define NE 1600000
#define NPB 256            // nodes per bucket
#define NB 391             // ceil(NN/NPB); NB*NPB = 100096
#define CHUNK 4096         // edges per partition block
#define NCB 391            // ceil(NE/CHUNK)
#define MAXB 5120          // per-bucket edge cap (mean 4096, +16 sigma)

// Partition (+ fused small GEMM in the extra block NCB).
__global__ __launch_bounds__(256) void k_part(const int* __restrict__ src,
                                              const int* __restrict__ dst,
                                              const float* __restrict__ W1,
                                              const float* __restrict__ W2,
                                              const float* __restrict__ b1,
                                              int* __restrict__ packed,
                                              int* __restrict__ scanT,
                                              float* __restrict__ W12,
                                              float* __restrict__ c1) {
    __shared__ int hist[NB];
    __shared__ int sc[256];
    __shared__ int cur[NB];
    __shared__ int buf[CHUNK];
    int c = blockIdx.x, t = threadIdx.x;
    if (c == NCB) {   // fused k_small
        for (int o = t; o < 640; o += 256) {
            int k = o / 10, ch = o - k * 10;
            float acc = 0.f;
            #pragma unroll
            for (int m = 0; m < 64; ++m) acc = fmaf(W1[k * 64 + m], W2[m * 10 + ch], acc);
            W12[o] = acc;
        }
        if (t < 10) {
            float acc = 0.f;
            #pragma unroll
            for (int m = 0; m < 64; ++m) acc = fmaf(b1[m], W2[m * 10 + t], acc);
            c1[t] = acc;
        }
        return;
    }
    int e0 = c * CHUNK, e1 = min(e0 + CHUNK, NE);
    int n = e1 - e0;
    for (int i = t; i < NB; i += 256) hist[i] = 0;
    __syncthreads();
    int pk[16], bk[16];
    #pragma unroll
    for (int k = 0; k < 16; ++k) {
        int e = e0 + t + k * 256;
        if (e < e1) {
            int s = src[e], d = dst[e];
            pk[k] = (s << 8) | (d & 255);
            bk[k] = d >> 8;
            atomicAdd(&hist[bk[k]], 1);
        } else bk[k] = -1;
    }
    __syncthreads();
    // exclusive scan of hist[0..NB-1] via pair-compaction into 256-wide scan
    int i0 = 2 * t, i1 = 2 * t + 1;
    int h0 = (i0 < NB) ? hist[i0] : 0;
    int h1 = (i1 < NB) ? hist[i1] : 0;
    int ps = h0 + h1;
    sc[t] = ps; __syncthreads();
    for (int off = 1; off < 256; off <<= 1) {
        int a = (t >= off) ? sc[t - off] : 0;
        __syncthreads(); sc[t] += a; __syncthreads();
    }
    int exc = sc[t] - ps;
    if (i0 < NB) cur[i0] = exc;
    if (i1 < NB) cur[i1] = exc + h0;
    __syncthreads();
    for (int b = t; b < NB; b += 256) scanT[c * (NB + 1) + b] = e0 + cur[b];
    if (t == 0) scanT[c * (NB + 1) + NB] = e0 + n;
    __syncthreads();
    #pragma unroll
    for (int k = 0; k < 16; ++k) {
        if (bk[k] >= 0) {
            int pos = atomicAdd(&cur[bk[k]], 1);
            buf[pos] = pk[k];
        }
    }
    __syncthreads();
    for (int i = t; i < n; i += 256) packed[e0 + i] = buf[i];
}

// Per-bucket counting sort + fused projection of the bucket's own 256 rows.
// LDS alias: phase1 stage[MAXB] (20480 B) | phase2 tile[64*65]+Wl[640]+ot[64*16].
__global__ __launch_bounds__(256) void k_sortproj(const int* __restrict__ packed,
                                                  const int* __restrict__ scanT,
                                                  const float* __restrict__ x,
                                                  const float* __restrict__ W12g,
                                                  int* __restrict__ ssrc,
                                                  int2* __restrict__ rowbe,
                                                  float* __restrict__ dis,
                                                  float* __restrict__ yd) {
    __shared__ __align__(16) char smem[23296];
    __shared__ int cnt[NPB];
    __shared__ int sc[256];
    __shared__ int cur[NPB];
    __shared__ float disl[NPB];
    __shared__ int stot;
    int b = blockIdx.x, t = threadIdx.x;
    int* stage = (int*)smem;

    // ---- phase 1: gather segments, 256-way counting sort ----
    cnt[t] = 0;
    if (t == 0) stot = 0;
    __syncthreads();
    for (int c = t; c < NCB; c += 256) {
        int s0 = scanT[c * (NB + 1) + b];
        int s1 = scanT[c * (NB + 1) + b + 1];
        int m = s1 - s0;
        if (m > 0) {
            int base = atomicAdd(&stot, m);
            for (int j = 0; j < m; ++j) {
                int p = packed[s0 + j];
                if (base + j < MAXB) stage[base + j] = p;
                atomicAdd(&cnt[p & 255], 1);
            }
        }
    }
    __syncthreads();
    int T = min(stot, MAXB);
    int h = cnt[t];
    sc[t] = h; __syncthreads();
    for (int off = 1; off < 256; off <<= 1) {
        int a = (t >= off) ? sc[t - off] : 0;
        __syncthreads(); sc[t] += a; __syncthreads();
    }
    int exc = sc[t] - h;
    int wbase = b * MAXB;
    int nidx = b * NPB + t;
    float dh = rsqrtf((float)h + 1.0f);
    disl[t] = dh;
    if (nidx < NN) {
        rowbe[nidx] = make_int2(wbase + exc, wbase + exc + h);
        dis[nidx] = dh;
    }
    cur[t] = wbase + exc;
    __syncthreads();
    for (int i = t; i < T; i += 256) {
        int p = stage[i];
        int pos = atomicAdd(&cur[p & 255], 1);
        ssrc[pos] = p >> 8;
    }
    __syncthreads();   // stage dead after this; smem reused below

    // ---- phase 2: project this bucket's 256 rows ----
    float* tile = (float*)smem;               // [64][65]   16640 B
    float* Wl   = (float*)(smem + 16640);     // [640]       2560 B
    float* ot   = (float*)(smem + 19200);     // [64][16]    4096 B
    for (int i = t; i < 640; i += 256) Wl[i] = W12g[i];
    for (int ts = 0; ts < 4; ++ts) {
        int gbase = b * NPB + ts * 64;
        __syncthreads();   // Wl ready (first iter) / prev writeout done
        for (int i = t; i < 64 * 16; i += 256) {
            int r = i >> 4, q = i & 15;
            if (gbase + r < NN) {
                float4 v = *(const float4*)&x[(gbase + r) * 64 + q * 4];
                tile[r * 65 + q * 4 + 0] = v.x;
                tile[r * 65 + q * 4 + 1] = v.y;
                tile[r * 65 + q * 4 + 2] = v.z;
                tile[r * 65 + q * 4 + 3] = v.w;
            }
        }
        for (int i = t; i < 1024; i += 256) ot[i] = 0.f;
        __syncthreads();
        for (int o = t; o < 640; o += 256) {
            int r = o / 10, ch = o - r * 10;
            if (gbase + r < NN) {
                float acc = 0.f;
                #pragma unroll
                for (int k = 0; k < 64; ++k) acc = fmaf(tile[r * 65 + k], Wl[k * 10 + ch], acc);
                ot[r * 16 + ch] = disl[ts * 64 + r] * acc;
            }
        }
        if (t < 64) ot[t * 16 + 10] = disl[ts * 64 + t];
        __syncthreads();
        for (int i = t; i < 256; i += 256) {
            int r = i >> 2, q = i & 3;
            if (q < 3 && gbase + r < NN)
                *(float4*)&yd[(gbase + r) * 16 + q * 4] = ((const float4*)ot)[r * 4 + q];
        }
    }
}

// Pass 1: 4 lanes/node, lane q<3 gathers float4; 4-deep unroll.
// zd[n][c<10] = dis^2*(yd self+nbrs); zd[n][10] = dis*(...); zd[n][11] = 0.
__global__ __launch_bounds__(256) void k_aggA(const float* __restrict__ yd,
                                              const float* __restrict__ dis,
                                              const int2* __restrict__ rowbe,
                                              const int* __restrict__ ssrc,
                                              float* __restrict__ zd) {
    int t = blockIdx.x * blockDim.x + threadIdx.x;
    int n = t >> 2, q = t & 3;
    if (n >= NN) return;
    int2 be = rowbe[n];
    const bool act = (q < 3);
    float4 a0 = make_float4(0.f, 0.f, 0.f, 0.f), a1 = a0, a2 = a0, a3 = a0;
    if (act) a0 = *(const float4*)&yd[n * 16 + q * 4];   // self term
    int j = be.x;
    for (; j + 3 < be.y; j += 4) {
        int s0 = ssrc[j], s1 = ssrc[j + 1], s2 = ssrc[j + 2], s3 = ssrc[j + 3];
        if (act) {
            float4 v0 = *(const float4*)&yd[s0 * 16 + q * 4];
            float4 v1 = *(const float4*)&yd[s1 * 16 + q * 4];
            float4 v2 = *(const float4*)&yd[s2 * 16 + q * 4];
            float4 v3 = *(const float4*)&yd[s3 * 16 + q * 4];
            a0.x += v0.x; a0.y += v0.y; a0.z += v0.z; a0.w += v0.w;
            a1.x += v1.x; a1.y += v1.y; a1.z += v1.z; a1.w += v1.w;
            a2.x += v2.x; a2.y += v2.y; a2.z += v2.z; a2.w += v2.w;
            a3.x += v3.x; a3.y += v3.y; a3.z += v3.z; a3.w += v3.w;
        }
    }
    for (; j < be.y; ++j) {
        int s = ssrc[j];
        if (act) {
            float4 v = *(const float4*)&yd[s * 16 + q * 4];
            a0.x += v.x; a0.y += v.y; a0.z += v.z; a0.w += v.w;
        }
    }
    if (act) {
        float4 s;
        s.x = (a0.x + a1.x) + (a2.x + a3.x);
        s.y = (a0.y + a1.y) + (a2.y + a3.y);
        s.z = (a0.z + a1.z) + (a2.z + a3.z);
        s.w = (a0.w + a1.w) + (a2.w + a3.w);
        float d = dis[n], d2 = d * d;
        if (q < 2) { s.x *= d2; s.y *= d2; s.z *= d2; s.w *= d2; }
        else       { s.x *= d2; s.y *= d2; s.z *= d;  s.w  = 0.f; }
        *(float4*)&zd[n * 16 + q * 4] = s;
    }
}

// Pass 2: out[n][c] = dis*(zd self+nbrs)[c] + zd[n][10]*c1[c] + b2[c].
__global__ __launch_bounds__(256) void k_aggB(const float* __restrict__ zd,
                                              const float* __restrict__ dis,
                                              const int2* __restrict__ rowbe,
                                              const int* __restrict__ ssrc,
                                              const float* __restrict__ c1,
                                              const float* __restrict__ b2,
                                              float* __restrict__ out) {
    int t = blockIdx.x * blockDim.x + threadIdx.x;
    int n = t >> 2, q = t & 3;
    if (n >= NN) return;
    int2 be = rowbe[n];
    const bool act = (q < 3);
    float4 self = make_float4(0.f, 0.f, 0.f, 0.f);
    if (act) self = *(const float4*)&zd[n * 16 + q * 4];
    float4 a0 = self, a1 = make_float4(0.f, 0.f, 0.f, 0.f), a2 = a1, a3 = a1;
    int j = be.x;
    for (; j + 3 < be.y; j += 4) {
        int s0 = ssrc[j], s1 = ssrc[j + 1], s2 = ssrc[j + 2], s3 = ssrc[j + 3];
        if (act) {
            float4 v0 = *(const float4*)&zd[s0 * 16 + q * 4];
            float4 v1 = *(const float4*)&zd[s1 * 16 + q * 4];
            float4 v2 = *(const float4*)&zd[s2 * 16 + q * 4];
            float4 v3 = *(const float4*)&zd[s3 * 16 + q * 4];
            a0.x += v0.x; a0.y += v0.y; a0.z += v0.z; a0.w += v0.w;
            a1.x += v1.x; a1.y += v1.y; a1.z += v1.z; a1.w += v1.w;
            a2.x += v2.x; a2.y += v2.y; a2.z += v2.z; a2.w += v2.w;
            a3.x += v3.x; a3.y += v3.y; a3.z += v3.z; a3.w += v3.w;
        }
    }
    for (; j < be.y; ++j) {
        int s = ssrc[j];
        if (act) {
            float4 v = *(const float4*)&zd[s * 16 + q * 4];
            a0.x += v.x; a0.y += v.y; a0.z += v.z; a0.w += v.w;
        }
    }
    float4 s;
    s.x = (a0.x + a1.x) + (a2.x + a3.x);
    s.y = (a0.y + a1.y) + (a2.y + a3.y);
    s.z = (a0.z + a1.z) + (a2.z + a3.z);
    s.w = (a0.w + a1.w) + (a2.w + a3.w);
    float n1 = __shfl(self.z, 2, 4);   // zd[n][10] from q2's self load
    float d = dis[n];
    if (q == 0) {
        out[n * 10 + 0] = fmaf(d, s.x, fmaf(n1, c1[0], b2[0]));
        out[n * 10 + 1] = fmaf(d, s.y, fmaf(n1, c1[1], b2[1]));
        out[n * 10 + 2] = fmaf(d, s.z, fmaf(n1, c1[2], b2[2]));
        out[n * 10 + 3] = fmaf(d, s.w, fmaf(n1, c1[3], b2[3]));
    } else if (q == 1) {
        out[n * 10 + 4] = fmaf(d, s.x, fmaf(n1, c1[4], b2[4]));
        out[n * 10 + 5] = fmaf(d, s.y, fmaf(n1, c1[5], b2[5]));
        out[n * 10 + 6] = fmaf(d, s.z, fmaf(n1, c1[6], b2[6]));
        out[n * 10 + 7] = fmaf(d, s.w, fmaf(n1, c1[7], b2[7]));
    } else if (q == 2) {
        out[n * 10 + 8] = fmaf(d, s.x, fmaf(n1, c1[8], b2[8]));
        out[n * 10 + 9] = fmaf(d, s.y, fmaf(n1, c1[9], b2[9]));
    }
}

extern "C" void kernel_launch(void* const* d_in, const int* in_sizes, int n_in,
                              void* d_out, int out_size, void* d_ws, size_t ws_size,
                              hipStream_t stream) {
    const float* x  = (const float*)d_in[0];
    const float* W1 = (const float*)d_in[1];
    const float* b1 = (const float*)d_in[2];
    const float* W2 = (const float*)d_in[3];
    const float* b2 = (const float*)d_in[4];
    const int* edge = (const int*)d_in[5];   // [2, NE]: src row then dst row
    const int* src = edge;
    const int* dst = edge + NE;
    float* out = (float*)d_out;

    // Workspace layout (64B-aligned), total ~29.0 MB:
    char* W = (char*)d_ws;
    float* yd     = (float*)(W);                   // NN*16 f     = 6,400,000 B
    float* zd     = (float*)(W + 6400000);         // NN*16 f     = 6,400,000 B
    float* dis    = (float*)(W + 12800000);        // NN f        =   400,000 B
    int*   packed = (int*)  (W + 13200000);        // NE i        = 6,400,000 B
    int*   scanT  = (int*)  (W + 19600000);        // NCB*(NB+1)  =   613,088 B
    int*   ssrc   = (int*)  (W + 20213120);        // NB*MAXB i   = 8,007,680 B
    int2*  rowbe  = (int2*) (W + 28220800);        // NN int2     =   800,000 B
    float* W12    = (float*)(W + 29020800);        // 640 f
    float* c1     = (float*)(W + 29023360);        // 10 f

    k_part    <<<NCB + 1, 256, 0, stream>>>(src, dst, W1, W2, b1, packed, scanT, W12, c1);
    k_sortproj<<<NB, 256, 0, stream>>>(packed, scanT, x, W12, ssrc, rowbe, dis, yd);
    k_aggA    <<<(NN * 4 + 255) / 256, 256, 0, stream>>>(yd, dis, rowbe, ssrc, zd);
    k_aggB    <<<(NN * 4 + 255) / 256, 256, 0, stream>>>(zd, dis, rowbe, ssrc, c1, b2, out);
}